// Round 6
// baseline (138.131 us; speedup 1.0000x reference)
//
#include <hip/hip_runtime.h>
#include <hip/hip_bf16.h>
#include <float.h>

// B=4096, D=512, N=8192, temp=0.5
#define BN_ 4096
#define DD  512
#define NN  8192
#define SCALE 2.0f   // 1/temperature
#define NTILE 2080   // 64*65/2 lower-triangle 128x128 tiles

typedef unsigned short u16;
typedef __attribute__((ext_vector_type(8))) short short8;   // 8 bf16 = 4 VGPRs
typedef __attribute__((ext_vector_type(4))) float floatx4;  // MFMA acc

struct alignas(8) U16x4 { u16 x, y, z, w; };

__device__ __forceinline__ u16 f2bf(float f) {
    union { float f; unsigned u; } c; c.f = f;
    unsigned u = c.u;
    unsigned r = (u + 0x7fffu + ((u >> 16) & 1u)) >> 16;   // RNE
    return (u16)r;
}

__device__ __forceinline__ void async_copy16(const u16* g, u16* l) {
    __builtin_amdgcn_global_load_lds(
        (const __attribute__((address_space(1))) void*)g,
        (__attribute__((address_space(3))) void*)l, 16, 0, 0);
}

// ------ kernel 1: fp32 -> bf16 concat + per-block positive-dot partial ------
// 1024 blocks x 8 floats/thread (2xfloat4 reads, short8 stores per stream).
// NO atomics; block partial -> Pos[bid]; lse_kernel folds them.  Block 0
// zero-inits d_out (harness poisons it with 0xAA).
__global__ __launch_bounds__(256) void convert_pos_kernel(const float* __restrict__ hi,
                                                          const float* __restrict__ hj,
                                                          u16* __restrict__ H,
                                                          float* __restrict__ Pos,
                                                          float* __restrict__ out) {
    __shared__ float red[4];
    int t = blockIdx.x * 256 + threadIdx.x;     // 1024 blocks -> 262144 threads
    int e = t * 8;
    const int BD = BN_ * DD;
    float4 a0 = *(const float4*)(hi + e), a1 = *(const float4*)(hi + e + 4);
    float4 b0 = *(const float4*)(hj + e), b1 = *(const float4*)(hj + e + 4);
    short8 oa, ob;
    oa[0] = (short)f2bf(a0.x); oa[1] = (short)f2bf(a0.y);
    oa[2] = (short)f2bf(a0.z); oa[3] = (short)f2bf(a0.w);
    oa[4] = (short)f2bf(a1.x); oa[5] = (short)f2bf(a1.y);
    oa[6] = (short)f2bf(a1.z); oa[7] = (short)f2bf(a1.w);
    ob[0] = (short)f2bf(b0.x); ob[1] = (short)f2bf(b0.y);
    ob[2] = (short)f2bf(b0.z); ob[3] = (short)f2bf(b0.w);
    ob[4] = (short)f2bf(b1.x); ob[5] = (short)f2bf(b1.y);
    ob[6] = (short)f2bf(b1.z); ob[7] = (short)f2bf(b1.w);
    *(short8*)(H + e) = oa;
    *(short8*)(H + BD + e) = ob;
    float dot = a0.x * b0.x + a0.y * b0.y + a0.z * b0.z + a0.w * b0.w
              + a1.x * b1.x + a1.y * b1.y + a1.z * b1.z + a1.w * b1.w;
#pragma unroll
    for (int msk = 1; msk < 64; msk <<= 1) dot += __shfl_xor(dot, msk);
    int lane = threadIdx.x & 63, wid = threadIdx.x >> 6;
    if (lane == 0) red[wid] = dot;
    __syncthreads();
    if (threadIdx.x == 0) {
        Pos[blockIdx.x] = red[0] + red[1] + red[2] + red[3];
        if (blockIdx.x == 0) *out = 0.0f;
    }
}

// ------------- kernel 2: symmetric Gram, lower-triangle 128x128 tiles -------------
// EXACT round-0 K-loop schedule.  Round-6 delta: VGPR diet so __launch_bounds__
// (256,4) fits WITHOUT spills (r5: compiler squeezed 76->64 VGPR by spilling
// ~12 dwords/thread -> 31 MB scratch writes, net loss):
//  (a) staging addresses: chunk c=j*256+tid has row&7 j-independent, so ONE
//      per-thread swizzled source base + uniform j*32*DD stride, ONE LDS base
//      + j*2048 (replaces 4 pointers + 4 offsets).
//  (b) A-fragment streamed one-at-a-time (peak live frags 20 VGPR, not 32).
// Keeps: 32 KB LDS (epilogue aliases onto As), bijective XCD swizzle.
__global__ __launch_bounds__(256, 4) void gram_kernel(const u16* __restrict__ H,
                                                      float* __restrict__ Mpart,
                                                      float* __restrict__ Spart) {
    __shared__ u16 As[128 * 64];    // 16 KB
    __shared__ u16 Bs[128 * 64];    // 16 KB   (total LDS = 32768 B exactly)

    // epilogue scratch aliases (used only after the K-loop's final barrier)
    float* Rm = (float*)&As[0];          // [2][128]
    float* Rs = Rm + 256;                // [2][128]
    float* Cm = Rs + 256;                // [2][128]
    float* Cs = Cm + 256;                // [2][128]

    const int tid  = threadIdx.x;
    const int lane = tid & 63;
    const int wid  = tid >> 6;
    const int quad = lane >> 4;
    const int ln15 = lane & 15;
    const int wr = wid >> 1, wc = wid & 1;

    // bijective XCD swizzle (2080 % 8 == 0)
    int t = ((int)blockIdx.x & 7) * (NTILE / 8) + ((int)blockIdx.x >> 3);

    // lower-triangle decode: t in [0, 2080)
    int bi = (int)((sqrtf(8.0f * (float)t + 1.0f) - 1.0f) * 0.5f);
    while ((bi + 1) * (bi + 2) / 2 <= t) bi++;
    while (bi * (bi + 1) / 2 > t) bi--;
    const int bj = t - bi * (bi + 1) / 2;
    const bool diag = (bi == bj);
    const int biBase = bi * 128, bjBase = bj * 128;

    // staging: chunk c = j*256+tid -> row = j*32 + (tid>>3); since (j*32)&7 == 0,
    // row&7 = (tid>>3)&7 for all j -> swizzled k-slot is j-independent.
    const int rowT = tid >> 3;                           // 0..31
    const int kcT  = ((tid & 7) ^ (rowT & 7)) * 8;       // swizzle on source side
    const u16* __restrict__ srcA0 = H + (size_t)(biBase + rowT) * DD + kcT;
    const ptrdiff_t dB = (ptrdiff_t)(bjBase - biBase) * DD;
    const ptrdiff_t dJ = (ptrdiff_t)32 * DD;             // per-j uniform stride
    u16* ldsA0 = &As[tid * 8];
    u16* ldsB0 = &Bs[tid * 8];

    floatx4 acc[4][4];
#pragma unroll
    for (int i = 0; i < 4; i++)
#pragma unroll
        for (int j = 0; j < 4; j++) acc[i][j] = (floatx4)0.0f;

    for (int k0 = 0; k0 < DD; k0 += 64) {
#pragma unroll
        for (int j = 0; j < 4; j++)
            async_copy16(srcA0 + j * dJ + k0,      ldsA0 + j * 2048);
#pragma unroll
        for (int j = 0; j < 4; j++)
            async_copy16(srcA0 + dB + j * dJ + k0, ldsB0 + j * 2048);
        __syncthreads();

#pragma unroll
        for (int kk = 0; kk < 2; kk++) {
            int ck = kk * 4 + quad;     // K-chunk 0..7 within the 64-wide tile
            short8 b[4];
#pragma unroll
            for (int tn = 0; tn < 4; tn++) {
                int r = wc * 64 + tn * 16 + ln15;
                b[tn] = *(const short8*)&Bs[(r * 8 + (ck ^ (r & 7))) * 8];
            }
#pragma unroll
            for (int tm = 0; tm < 4; tm++) {
                int r = wr * 64 + tm * 16 + ln15;
                short8 a = *(const short8*)&As[(r * 8 + (ck ^ (r & 7))) * 8];
#pragma unroll
                for (int tn = 0; tn < 4; tn++)
                    acc[tm][tn] = __builtin_amdgcn_mfma_f32_16x16x32_bf16(
                        a, b[tn], acc[tm][tn], 0, 0, 0);
            }
        }
        __syncthreads();
    }

    // scale in place; mask self-similarity on diagonal tiles
    // C/D layout: local row = tm*16 + quad*4 + reg, local col = tn*16 + ln15
#pragma unroll
    for (int tm = 0; tm < 4; tm++)
#pragma unroll
        for (int tn = 0; tn < 4; tn++)
#pragma unroll
            for (int r = 0; r < 4; r++) {
                float v = SCALE * acc[tm][tn][r];
                if (diag) {
                    int lrow = wr * 64 + tm * 16 + quad * 4 + r;
                    int lcol = wc * 64 + tn * 16 + ln15;
                    if (lrow == lcol) v = -FLT_MAX;
                }
                acc[tm][tn][r] = v;
            }

    // row pass: per-row max+sumexp over this wave's 64 cols
#pragma unroll
    for (int tm = 0; tm < 4; tm++) {
#pragma unroll
        for (int r = 0; r < 4; r++) {
            float vmax = -FLT_MAX;
#pragma unroll
            for (int tn = 0; tn < 4; tn++) vmax = fmaxf(vmax, acc[tm][tn][r]);
#pragma unroll
            for (int msk = 1; msk < 16; msk <<= 1)
                vmax = fmaxf(vmax, __shfl_xor(vmax, msk));
            float s = 0.0f;
#pragma unroll
            for (int tn = 0; tn < 4; tn++) s += __expf(acc[tm][tn][r] - vmax);
#pragma unroll
            for (int msk = 1; msk < 16; msk <<= 1) s += __shfl_xor(s, msk);
            if (ln15 == 0) {
                int x = wr * 64 + tm * 16 + quad * 4 + r;
                Rm[wc * 128 + x] = vmax; Rs[wc * 128 + x] = s;
            }
        }
    }

    // col pass (transpose tile): per-col max+sumexp over this wave's 64 rows
    if (!diag) {
#pragma unroll
        for (int tn = 0; tn < 4; tn++) {
            float cm = -FLT_MAX;
#pragma unroll
            for (int tm = 0; tm < 4; tm++)
#pragma unroll
                for (int r = 0; r < 4; r++) cm = fmaxf(cm, acc[tm][tn][r]);
            cm = fmaxf(cm, __shfl_xor(cm, 16));
            cm = fmaxf(cm, __shfl_xor(cm, 32));
            float s = 0.0f;
#pragma unroll
            for (int tm = 0; tm < 4; tm++)
#pragma unroll
                for (int r = 0; r < 4; r++) s += __expf(acc[tm][tn][r] - cm);
            s += __shfl_xor(s, 16);
            s += __shfl_xor(s, 32);
            if (quad == 0) {
                int y = wc * 64 + tn * 16 + ln15;
                Cm[wr * 128 + y] = cm; Cs[wr * 128 + y] = s;
            }
        }
    }
    __syncthreads();

    // merge wave halves, write slot-major partials: Mpart[slot*NN + globalRow]
    if (tid < 128) {
        float m0 = Rm[tid], m1 = Rm[128 + tid];
        float s0 = Rs[tid], s1 = Rs[128 + tid];
        float m = fmaxf(m0, m1);
        float s = s0 * __expf(m0 - m) + s1 * __expf(m1 - m);
        Mpart[(size_t)bj * NN + biBase + tid] = m;
        Spart[(size_t)bj * NN + biBase + tid] = s;
    } else if (!diag) {
        int y = tid - 128;
        float m0 = Cm[y], m1 = Cm[128 + y];
        float s0 = Cs[y], s1 = Cs[128 + y];
        float m = fmaxf(m0, m1);
        float s = s0 * __expf(m0 - m) + s1 * __expf(m1 - m);
        Mpart[(size_t)bi * NN + bjBase + y] = m;
        Spart[(size_t)bi * NN + bjBase + y] = s;
    }
}

// ------ kernel 3: combine 64 slot-partials per row + pos partials -> loss ------
// 128 blocks x 64 rows; each wave covers 16 slots of its 64 rows, merged in LDS.
__global__ __launch_bounds__(256) void lse_kernel(const float* __restrict__ Mpart,
                                                  const float* __restrict__ Spart,
                                                  const float* __restrict__ Pos,
                                                  float* __restrict__ out) {
    __shared__ float sm[4][64], ss[4][64];
    __shared__ float red[256];
    int tid = threadIdx.x;
    int wid = tid >> 6, lane = tid & 63;
    int r = blockIdx.x * 64 + lane;
    float m = -FLT_MAX, s = 0.0f;
#pragma unroll
    for (int i = 0; i < 16; i++) {
        int c = wid * 16 + i;
        float mc = Mpart[(size_t)c * NN + r];   // coalesced: lane-stride 4B
        float sc = Spart[(size_t)c * NN + r];
        float mn = fmaxf(m, mc);
        s = s * __expf(m - mn) + sc * __expf(mc - mn);
        m = mn;
    }
    sm[wid][lane] = m; ss[wid][lane] = s;
    __syncthreads();
    float v = 0.0f;
    if (tid < 64) {
        float m0 = sm[0][tid], m1 = sm[1][tid], m2 = sm[2][tid], m3 = sm[3][tid];
        float mm = fmaxf(fmaxf(m0, m1), fmaxf(m2, m3));
        float sa = ss[0][tid] * __expf(m0 - mm) + ss[1][tid] * __expf(m1 - mm)
                 + ss[2][tid] * __expf(m2 - mm) + ss[3][tid] * __expf(m3 - mm);
        v = mm + logf(sa);
        // 1024 convert-block partials; this block's share is 8 of them
        if (tid < 8) v += -4.0f * Pos[blockIdx.x * 8 + tid];
    }
    red[tid] = v;
    __syncthreads();
    for (int st = 128; st > 0; st >>= 1) {
        if (tid < st) red[tid] += red[tid + st];
        __syncthreads();
    }
    if (tid == 0) atomicAdd(out, red[0] * (1.0f / (float)NN));
}

extern "C" void kernel_launch(void* const* d_in, const int* in_sizes, int n_in,
                              void* d_out, int out_size, void* d_ws, size_t ws_size,
                              hipStream_t stream) {
    const float* hi = (const float*)d_in[0];
    const float* hj = (const float*)d_in[1];
    float* out = (float*)d_out;

    u16*   H     = (u16*)d_ws;                                            // 8 MB
    float* Mpart = (float*)((char*)d_ws + (size_t)8 * 1024 * 1024);       // 2 MB
    float* Spart = (float*)((char*)d_ws + (size_t)10 * 1024 * 1024);      // 2 MB
    float* Pos   = (float*)((char*)d_ws + (size_t)12 * 1024 * 1024);      // 4 KB

    convert_pos_kernel<<<1024, 256, 0, stream>>>(hi, hj, H, Pos, out);

    gram_kernel<<<NTILE, 256, 0, stream>>>(H, Mpart, Spart);

    lse_kernel<<<128, 256, 0, stream>>>(Mpart, Spart, Pos, out);
}

// Round 7
// 133.932 us; speedup vs baseline: 1.0314x; 1.0314x over previous
//
#include <hip/hip_runtime.h>
#include <hip/hip_bf16.h>
#include <float.h>

// B=4096, D=512, N=8192, temp=0.5
#define BN_ 4096
#define DD  512
#define NN  8192
#define SCALE 2.0f   // 1/temperature
#define NTILE 2080   // 64*65/2 lower-triangle 128x128 tiles

typedef unsigned short u16;
typedef __attribute__((ext_vector_type(8))) short short8;   // 8 bf16 = 4 VGPRs
typedef __attribute__((ext_vector_type(4))) float floatx4;  // MFMA acc

struct alignas(8) U16x4 { u16 x, y, z, w; };

__device__ __forceinline__ u16 f2bf(float f) {
    union { float f; unsigned u; } c; c.f = f;
    unsigned u = c.u;
    unsigned r = (u + 0x7fffu + ((u >> 16) & 1u)) >> 16;   // RNE
    return (u16)r;
}

__device__ __forceinline__ void async_copy16(const u16* g, u16* l) {
    __builtin_amdgcn_global_load_lds(
        (const __attribute__((address_space(1))) void*)g,
        (__attribute__((address_space(3))) void*)l, 16, 0, 0);
}

// ------ kernel 1: fp32 -> bf16 concat + per-block positive-dot partial ------
// EXACT round-0 version (r6's 8-float variant measured ~6 us slower; reverted).
// NO atomics; block partial -> Pos[bid].  Block 0 zero-inits d_out.
__global__ __launch_bounds__(256) void convert_pos_kernel(const float* __restrict__ hi,
                                                          const float* __restrict__ hj,
                                                          u16* __restrict__ H,
                                                          float* __restrict__ Pos,
                                                          float* __restrict__ out) {
    __shared__ float red[4];
    int t = blockIdx.x * 256 + threadIdx.x;     // 2048 blocks -> 524288 threads
    int e = t * 4;
    const int BD = BN_ * DD;
    float4 a = *(const float4*)(hi + e);
    float4 b = *(const float4*)(hj + e);
    U16x4 oa, ob;
    oa.x = f2bf(a.x); oa.y = f2bf(a.y); oa.z = f2bf(a.z); oa.w = f2bf(a.w);
    ob.x = f2bf(b.x); ob.y = f2bf(b.y); ob.z = f2bf(b.z); ob.w = f2bf(b.w);
    *(U16x4*)(H + e) = oa;
    *(U16x4*)(H + BD + e) = ob;
    float dot = a.x * b.x + a.y * b.y + a.z * b.z + a.w * b.w;
#pragma unroll
    for (int msk = 1; msk < 64; msk <<= 1) dot += __shfl_xor(dot, msk);
    int lane = threadIdx.x & 63, wid = threadIdx.x >> 6;
    if (lane == 0) red[wid] = dot;
    __syncthreads();
    if (threadIdx.x == 0) {
        Pos[blockIdx.x] = red[0] + red[1] + red[2] + red[3];
        if (blockIdx.x == 0) *out = 0.0f;
    }
}

// ------------- kernel 2: symmetric Gram, lower-triangle 128x128 tiles -------------
// Round-7 delta: SAME tile / K-loop / LDS / swizzle as round-0, but 8 waves
// (512 threads) with 64x32 wave-tiles -> acc[4][2] = 32 AGPR (vs 64).
// Register math (m69 thresholds: <=128 regs -> 4 waves/EU): r0's 4-wave kernel
// needs 76 arch + 64 acc = 140 > 128 -> stuck at 8 waves/CU, and forcing (256,4)
// just spilled (r5/r6: 31-44 MB scratch writes).  This shape needs ~75 arch + 32
// acc ~= 107 <= 128 -> __launch_bounds__(512,4) is satisfiable WITHOUT spills:
// 2 blocks/CU = 16 waves/CU, double r0's TLP for hiding the staging latency.
// Staging bytes, MFMA count, barrier structure per K-step: identical to r0.
__global__ __launch_bounds__(512, 4) void gram_kernel(const u16* __restrict__ H,
                                                      float* __restrict__ Mpart,
                                                      float* __restrict__ Spart) {
    __shared__ u16 As[128 * 64];    // 16 KB
    __shared__ u16 Bs[128 * 64];    // 16 KB   (total LDS = 32768 B)

    // epilogue scratch aliases (used only after the K-loop's final barrier)
    float* Rm = (float*)&As[0];          // [4 col-strips][128 rows]
    float* Rs = Rm + 512;                // [4][128]
    float* Cm = Rs + 512;                // [2 row-strips][128 cols]
    float* Cs = Cm + 256;                // [2][128]   (6 KB total, fits in As)

    const int tid  = threadIdx.x;
    const int lane = tid & 63;
    const int wid  = tid >> 6;        // 0..7
    const int quad = lane >> 4;
    const int ln15 = lane & 15;
    const int wr = wid >> 2;          // 0..1 : 64-row strip
    const int wc = wid & 3;           // 0..3 : 32-col strip

    // bijective XCD swizzle (2080 % 8 == 0); measured neutral, kept (harmless)
    int t = ((int)blockIdx.x & 7) * (NTILE / 8) + ((int)blockIdx.x >> 3);

    // lower-triangle decode: t in [0, 2080)
    int bi = (int)((sqrtf(8.0f * (float)t + 1.0f) - 1.0f) * 0.5f);
    while ((bi + 1) * (bi + 2) / 2 <= t) bi++;
    while (bi * (bi + 1) / 2 > t) bi--;
    const int bj = t - bi * (bi + 1) / 2;
    const bool diag = (bi == bj);
    const int biBase = bi * 128, bjBase = bj * 128;

    // staging: 1024 chunks/matrix, 512 threads -> 2 chunks each (j in {0,1}).
    // chunk c = j*512+tid: row = j*64 + (tid>>3); (j*64)&7 == 0 so the swizzled
    // k-slot (pos ^ row&7) is j-independent -> ONE per-thread source base +
    // uniform strides.  LDS dest = c*16B: wave-uniform base + lane*16B ✓.
    const int rowT = tid >> 3;                           // 0..63
    const int kcT  = ((tid & 7) ^ (rowT & 7)) * 8;       // swizzle on source side
    const u16* __restrict__ srcA0 = H + (size_t)(biBase + rowT) * DD + kcT;
    const ptrdiff_t dB = (ptrdiff_t)(bjBase - biBase) * DD;
    const ptrdiff_t dJ = (ptrdiff_t)64 * DD;             // j-stride (64 rows)
    u16* ldsA0 = &As[tid * 8];
    u16* ldsB0 = &Bs[tid * 8];

    floatx4 acc[4][2];
#pragma unroll
    for (int i = 0; i < 4; i++)
#pragma unroll
        for (int j = 0; j < 2; j++) acc[i][j] = (floatx4)0.0f;

    for (int k0 = 0; k0 < DD; k0 += 64) {
        async_copy16(srcA0 + k0,           ldsA0);
        async_copy16(srcA0 + dJ + k0,      ldsA0 + 4096);
        async_copy16(srcA0 + dB + k0,      ldsB0);
        async_copy16(srcA0 + dB + dJ + k0, ldsB0 + 4096);
        __syncthreads();

#pragma unroll
        for (int kk = 0; kk < 2; kk++) {
            int ck = kk * 4 + quad;     // K-chunk 0..7 within the 64-wide tile
            short8 b[2];
#pragma unroll
            for (int tn = 0; tn < 2; tn++) {
                int r = wc * 32 + tn * 16 + ln15;
                b[tn] = *(const short8*)&Bs[(r * 8 + (ck ^ (r & 7))) * 8];
            }
#pragma unroll
            for (int tm = 0; tm < 4; tm++) {
                int r = wr * 64 + tm * 16 + ln15;
                short8 a = *(const short8*)&As[(r * 8 + (ck ^ (r & 7))) * 8];
#pragma unroll
                for (int tn = 0; tn < 2; tn++)
                    acc[tm][tn] = __builtin_amdgcn_mfma_f32_16x16x32_bf16(
                        a, b[tn], acc[tm][tn], 0, 0, 0);
            }
        }
        __syncthreads();
    }

    // scale in place; mask self-similarity on diagonal tiles
    // C/D layout: local row = wr*64 + tm*16 + quad*4 + reg, col = wc*32 + tn*16 + ln15
#pragma unroll
    for (int tm = 0; tm < 4; tm++)
#pragma unroll
        for (int tn = 0; tn < 2; tn++)
#pragma unroll
            for (int r = 0; r < 4; r++) {
                float v = SCALE * acc[tm][tn][r];
                if (diag) {
                    int lrow = wr * 64 + tm * 16 + quad * 4 + r;
                    int lcol = wc * 32 + tn * 16 + ln15;
                    if (lrow == lcol) v = -FLT_MAX;
                }
                acc[tm][tn][r] = v;
            }

    // row pass: per-row max+sumexp over this wave's 32 cols
#pragma unroll
    for (int tm = 0; tm < 4; tm++) {
#pragma unroll
        for (int r = 0; r < 4; r++) {
            float vmax = fmaxf(acc[tm][0][r], acc[tm][1][r]);
#pragma unroll
            for (int msk = 1; msk < 16; msk <<= 1)
                vmax = fmaxf(vmax, __shfl_xor(vmax, msk));
            float s = __expf(acc[tm][0][r] - vmax) + __expf(acc[tm][1][r] - vmax);
#pragma unroll
            for (int msk = 1; msk < 16; msk <<= 1) s += __shfl_xor(s, msk);
            if (ln15 == 0) {
                int x = wr * 64 + tm * 16 + quad * 4 + r;
                Rm[wc * 128 + x] = vmax; Rs[wc * 128 + x] = s;
            }
        }
    }

    // col pass (transpose tile): per-col max+sumexp over this wave's 64 rows
    if (!diag) {
#pragma unroll
        for (int tn = 0; tn < 2; tn++) {
            float cm = -FLT_MAX;
#pragma unroll
            for (int tm = 0; tm < 4; tm++)
#pragma unroll
                for (int r = 0; r < 4; r++) cm = fmaxf(cm, acc[tm][tn][r]);
            cm = fmaxf(cm, __shfl_xor(cm, 16));
            cm = fmaxf(cm, __shfl_xor(cm, 32));
            float s = 0.0f;
#pragma unroll
            for (int tm = 0; tm < 4; tm++)
#pragma unroll
                for (int r = 0; r < 4; r++) s += __expf(acc[tm][tn][r] - cm);
            s += __shfl_xor(s, 16);
            s += __shfl_xor(s, 32);
            if (quad == 0) {
                int y = wc * 32 + tn * 16 + ln15;
                Cm[wr * 128 + y] = cm; Cs[wr * 128 + y] = s;
            }
        }
    }
    __syncthreads();

    // merge wave strips, write slot-major partials: Mpart[slot*NN + globalRow]
    if (tid < 128) {
        float m0 = Rm[tid], m1 = Rm[128 + tid], m2 = Rm[256 + tid], m3 = Rm[384 + tid];
        float mm = fmaxf(fmaxf(m0, m1), fmaxf(m2, m3));
        float s = Rs[tid] * __expf(m0 - mm) + Rs[128 + tid] * __expf(m1 - mm)
                + Rs[256 + tid] * __expf(m2 - mm) + Rs[384 + tid] * __expf(m3 - mm);
        Mpart[(size_t)bj * NN + biBase + tid] = mm;
        Spart[(size_t)bj * NN + biBase + tid] = s;
    } else if (tid < 256 && !diag) {
        int y = tid - 128;
        float m0 = Cm[y], m1 = Cm[128 + y];
        float mm = fmaxf(m0, m1);
        float s = Cs[y] * __expf(m0 - mm) + Cs[128 + y] * __expf(m1 - mm);
        Mpart[(size_t)bi * NN + bjBase + y] = mm;
        Spart[(size_t)bi * NN + bjBase + y] = s;
    }
}

// ------ kernel 3: combine 64 slot-partials per row + pos partials -> loss ------
// 128 blocks x 64 rows; each wave covers 16 slots of its 64 rows, merged in LDS.
__global__ __launch_bounds__(256) void lse_kernel(const float* __restrict__ Mpart,
                                                  const float* __restrict__ Spart,
                                                  const float* __restrict__ Pos,
                                                  float* __restrict__ out) {
    __shared__ float sm[4][64], ss[4][64];
    __shared__ float red[256];
    int tid = threadIdx.x;
    int wid = tid >> 6, lane = tid & 63;
    int r = blockIdx.x * 64 + lane;
    float m = -FLT_MAX, s = 0.0f;
#pragma unroll
    for (int i = 0; i < 16; i++) {
        int c = wid * 16 + i;
        float mc = Mpart[(size_t)c * NN + r];   // coalesced: lane-stride 4B
        float sc = Spart[(size_t)c * NN + r];
        float mn = fmaxf(m, mc);
        s = s * __expf(m - mn) + sc * __expf(mc - mn);
        m = mn;
    }
    sm[wid][lane] = m; ss[wid][lane] = s;
    __syncthreads();
    float v = 0.0f;
    if (tid < 64) {
        float m0 = sm[0][tid], m1 = sm[1][tid], m2 = sm[2][tid], m3 = sm[3][tid];
        float mm = fmaxf(fmaxf(m0, m1), fmaxf(m2, m3));
        float sa = ss[0][tid] * __expf(m0 - mm) + ss[1][tid] * __expf(m1 - mm)
                 + ss[2][tid] * __expf(m2 - mm) + ss[3][tid] * __expf(m3 - mm);
        v = mm + logf(sa);
        // 2048 convert-block partials; this block's share is 16 of them
        if (tid < 16) v += -4.0f * Pos[blockIdx.x * 16 + tid];
    }
    red[tid] = v;
    __syncthreads();
    for (int st = 128; st > 0; st >>= 1) {
        if (tid < st) red[tid] += red[tid + st];
        __syncthreads();
    }
    if (tid == 0) atomicAdd(out, red[0] * (1.0f / (float)NN));
}

extern "C" void kernel_launch(void* const* d_in, const int* in_sizes, int n_in,
                              void* d_out, int out_size, void* d_ws, size_t ws_size,
                              hipStream_t stream) {
    const float* hi = (const float*)d_in[0];
    const float* hj = (const float*)d_in[1];
    float* out = (float*)d_out;

    u16*   H     = (u16*)d_ws;                                            // 8 MB
    float* Mpart = (float*)((char*)d_ws + (size_t)8 * 1024 * 1024);       // 2 MB
    float* Spart = (float*)((char*)d_ws + (size_t)10 * 1024 * 1024);      // 2 MB
    float* Pos   = (float*)((char*)d_ws + (size_t)12 * 1024 * 1024);      // 8 KB

    convert_pos_kernel<<<2048, 256, 0, stream>>>(hi, hj, H, Pos, out);

    gram_kernel<<<NTILE, 512, 0, stream>>>(H, Mpart, Spart);

    lse_kernel<<<128, 256, 0, stream>>>(Mpart, Spart, Pos, out);
}